// Round 1
// baseline (1000.207 us; speedup 1.0000x reference)
//
#include <hip/hip_runtime.h>

// Problem constants (match reference)
#define IN_CH   128
#define HC      64      // channels per node at every layer boundary
#define NEG_SLOPE 0.2f

// ---------------------------------------------------------------------------
// CSR build: histogram of dst, exclusive scan, scatter src ids
// ---------------------------------------------------------------------------
__global__ __launch_bounds__(256) void hist_k(const int* __restrict__ ei, int* __restrict__ deg, int E) {
    int i = blockIdx.x * 256 + threadIdx.x;
    if (i < E) atomicAdd(&deg[ei[E + i]], 1);
}

__global__ __launch_bounds__(256) void scan1_k(const int* __restrict__ deg, int* __restrict__ tmp,
                                               int* __restrict__ bsum, int n) {
    __shared__ int s[256];
    int tid = threadIdx.x;
    int i = blockIdx.x * 256 + tid;
    int v = (i < n) ? deg[i] : 0;
    s[tid] = v; __syncthreads();
    for (int o = 1; o < 256; o <<= 1) {
        int t = (tid >= o) ? s[tid - o] : 0;
        __syncthreads();
        s[tid] += t;
        __syncthreads();
    }
    if (i < n) tmp[i] = s[tid] - v;          // exclusive within block
    if (tid == 255) bsum[blockIdx.x] = s[255]; // block total
}

__global__ __launch_bounds__(512) void scan2_k(int* __restrict__ bsum, int nb) {
    __shared__ int s[512];
    int tid = threadIdx.x;
    int v = (tid < nb) ? bsum[tid] : 0;
    s[tid] = v; __syncthreads();
    for (int o = 1; o < 512; o <<= 1) {
        int t = (tid >= o) ? s[tid - o] : 0;
        __syncthreads();
        s[tid] += t;
        __syncthreads();
    }
    if (tid < nb) bsum[tid] = s[tid] - v;    // exclusive block offsets
}

__global__ __launch_bounds__(256) void scan3_k(const int* __restrict__ tmp, const int* __restrict__ bsum,
                                               int* __restrict__ off, int* __restrict__ cursor,
                                               int n, int Etot) {
    int i = blockIdx.x * 256 + threadIdx.x;
    if (i < n) {
        int v = tmp[i] + bsum[blockIdx.x];
        off[i] = v;
        cursor[i] = v;
    }
    if (i == 0) off[n] = Etot;
}

__global__ __launch_bounds__(256) void scatter_k(const int* __restrict__ ei, int* __restrict__ cursor,
                                                 int* __restrict__ csr, int E) {
    int i = blockIdx.x * 256 + threadIdx.x;
    if (i < E) {
        int d = ei[E + i];
        int p = atomicAdd(&cursor[d], 1);
        csr[p] = ei[i];
    }
}

// ---------------------------------------------------------------------------
// GEMM  H[n,64] = X[n,K] @ W[K,64]  + fused attention-logit epilogue.
// One wave per row; lane = output channel. Logits reduced via shfl butterflies.
// ---------------------------------------------------------------------------
template<int K, int HEADS>
__global__ __launch_bounds__(256) void gemm_al_k(const float* __restrict__ X, const float* __restrict__ W,
                                                 const float* __restrict__ a_s, const float* __restrict__ a_d,
                                                 float* __restrict__ H, float* __restrict__ ALS,
                                                 float* __restrict__ ALD, int n) {
    int lane = threadIdx.x & 63;
    int row = (blockIdx.x << 2) + (threadIdx.x >> 6);
    if (row >= n) return;
    const float4* xv = (const float4*)(X + (size_t)row * K);
    float acc = 0.f;
#pragma unroll
    for (int k4 = 0; k4 < K / 4; k4++) {
        float4 xx = xv[k4];
        acc += xx.x * W[(k4 * 4 + 0) * 64 + lane];
        acc += xx.y * W[(k4 * 4 + 1) * 64 + lane];
        acc += xx.z * W[(k4 * 4 + 2) * 64 + lane];
        acc += xx.w * W[(k4 * 4 + 3) * 64 + lane];
    }
    H[(size_t)row * 64 + lane] = acc;

    // attention logits: a_s/a_d flat layout [head*hid + c] == lane index directly
    float vs = acc * a_s[lane];
    float vd = acc * a_d[lane];
#pragma unroll
    for (int m = 1; m <= 16; m <<= 1) {
        vs += __shfl_xor(vs, m, 64);
        vd += __shfl_xor(vd, m, 64);
    }
    if (HEADS == 1) {
        vs += __shfl_xor(vs, 32, 64);
        vd += __shfl_xor(vd, 32, 64);
        if (lane == 0) { ALS[row] = vs; ALD[row] = vd; }
    } else {
        if ((lane & 31) == 0) {
            ALS[(size_t)row * 2 + (lane >> 5)] = vs;
            ALD[(size_t)row * 2 + (lane >> 5)] = vd;
        }
    }
}

// ---------------------------------------------------------------------------
// Aggregation: one wave per dst node, lane = channel. Atomic-free.
// Softmax done without max-shift (scores are O(1), fp32-safe); self-loop inline.
// ---------------------------------------------------------------------------
template<int HEADS, int RELU>
__global__ __launch_bounds__(256) void aggregate_k(const float* __restrict__ H, const float* __restrict__ ALS,
                                                   const float* __restrict__ ALD, const int* __restrict__ off,
                                                   const int* __restrict__ csr, const float* __restrict__ bias,
                                                   float* __restrict__ OUT, int n) {
    int lane = threadIdx.x & 63;
    int dst = (blockIdx.x << 2) + (threadIdx.x >> 6);
    if (dst >= n) return;
    int head = (HEADS == 2) ? (lane >> 5) : 0;
    float ald = ALD[(size_t)dst * HEADS + head];

    // self-loop contribution
    float e = ALS[(size_t)dst * HEADS + head] + ald;
    e = (e >= 0.f) ? e : NEG_SLOPE * e;
    float ee = __expf(e);
    float den = ee;
    float acc = ee * H[(size_t)dst * 64 + lane];

    int b0 = off[dst], b1 = off[dst + 1];
    int i = b0;
    for (; i + 1 < b1; i += 2) {
        int s0 = csr[i], s1 = csr[i + 1];
        float e0 = ALS[(size_t)s0 * HEADS + head] + ald;
        float e1 = ALS[(size_t)s1 * HEADS + head] + ald;
        e0 = (e0 >= 0.f) ? e0 : NEG_SLOPE * e0;
        e1 = (e1 >= 0.f) ? e1 : NEG_SLOPE * e1;
        float w0 = __expf(e0);
        float w1 = __expf(e1);
        float h0 = H[(size_t)s0 * 64 + lane];
        float h1 = H[(size_t)s1 * 64 + lane];
        den += w0 + w1;
        acc += w0 * h0 + w1 * h1;
    }
    if (i < b1) {
        int s0 = csr[i];
        float e0 = ALS[(size_t)s0 * HEADS + head] + ald;
        e0 = (e0 >= 0.f) ? e0 : NEG_SLOPE * e0;
        float w0 = __expf(e0);
        den += w0;
        acc += w0 * H[(size_t)s0 * 64 + lane];
    }

    float o = acc / den + bias[lane];
    if (RELU) o = (o > 0.f) ? o : 0.f;
    OUT[(size_t)dst * 64 + lane] = o;
}

// ---------------------------------------------------------------------------
extern "C" void kernel_launch(void* const* d_in, const int* in_sizes, int n_in,
                              void* d_out, int out_size, void* d_ws, size_t ws_size,
                              hipStream_t stream) {
    const float* x   = (const float*)d_in[0];
    const int*   ei  = (const int*)  d_in[1];
    const float* W1  = (const float*)d_in[2];
    const float* as1 = (const float*)d_in[3];
    const float* ad1 = (const float*)d_in[4];
    const float* b1  = (const float*)d_in[5];
    const float* W2  = (const float*)d_in[6];
    const float* as2 = (const float*)d_in[7];
    const float* ad2 = (const float*)d_in[8];
    const float* b2  = (const float*)d_in[9];
    const float* W3  = (const float*)d_in[10];
    const float* as3 = (const float*)d_in[11];
    const float* ad3 = (const float*)d_in[12];
    const float* b3  = (const float*)d_in[13];

    const int N = in_sizes[0] / IN_CH;
    const int E = in_sizes[1] / 2;

    // workspace carve (256B aligned)
    char* p = (char*)d_ws;
    auto carve = [&](size_t bytes) {
        char* r = p;
        p += (bytes + 255) & ~(size_t)255;
        return r;
    };
    float* hbuf   = (float*)carve((size_t)N * HC * 4);
    float* obuf   = (float*)carve((size_t)N * HC * 4);
    float* als    = (float*)carve((size_t)N * 2 * 4);
    float* ald    = (float*)carve((size_t)N * 2 * 4);
    int*   deg    = (int*)  carve((size_t)N * 4);
    int*   cursor = (int*)  carve((size_t)N * 4);
    int*   off    = (int*)  carve((size_t)(N + 1) * 4);
    int*   tmp    = (int*)  carve((size_t)N * 4);
    int*   bsum   = (int*)  carve((size_t)((N + 255) / 256 + 1) * 4);
    int*   csr    = (int*)  carve((size_t)E * 4);

    const int NB = (N + 255) / 256;       // scan blocks (391 <= 512)
    const int EB = (E + 255) / 256;
    const int NW = (N + 3) / 4;           // one wave per node, 4 waves/block

    // ---- CSR build (shared by all 3 layers) ----
    hipMemsetAsync(deg, 0, (size_t)N * 4, stream);
    hist_k   <<<EB, 256, 0, stream>>>(ei, deg, E);
    scan1_k  <<<NB, 256, 0, stream>>>(deg, tmp, bsum, N);
    scan2_k  <<<1, 512, 0, stream>>>(bsum, NB);
    scan3_k  <<<NB, 256, 0, stream>>>(tmp, bsum, off, cursor, N, E);
    scatter_k<<<EB, 256, 0, stream>>>(ei, cursor, csr, E);

    // ---- Layer 1: IN=128 -> 2x32 concat, relu ----
    gemm_al_k<128, 2><<<NW, 256, 0, stream>>>(x, W1, as1, ad1, hbuf, als, ald, N);
    aggregate_k<2, 1><<<NW, 256, 0, stream>>>(hbuf, als, ald, off, csr, b1, obuf, N);

    // ---- Layer 2: 64 -> 2x32 concat, relu ----
    gemm_al_k<64, 2><<<NW, 256, 0, stream>>>(obuf, W2, as2, ad2, hbuf, als, ald, N);
    aggregate_k<2, 1><<<NW, 256, 0, stream>>>(hbuf, als, ald, off, csr, b2, obuf, N);

    // ---- Layer 3: 64 -> 64, 1 head, mean(=identity), no relu ----
    gemm_al_k<64, 1><<<NW, 256, 0, stream>>>(obuf, W3, as3, ad3, hbuf, als, ald, N);
    aggregate_k<1, 0><<<NW, 256, 0, stream>>>(hbuf, als, ald, off, csr, b3, (float*)d_out, N);
}

// Round 2
// 765.535 us; speedup vs baseline: 1.3065x; 1.3065x over previous
//
#include <hip/hip_runtime.h>

// Problem constants (match reference)
#define IN_CH   128
#define HC      64      // channels per node at every layer boundary
#define NEG_SLOPE 0.2f

// ---------------------------------------------------------------------------
// CSR build: histogram of dst, exclusive scan, scatter src ids
// ---------------------------------------------------------------------------
__global__ __launch_bounds__(256) void hist_k(const int* __restrict__ ei, int* __restrict__ deg, int E) {
    int i = blockIdx.x * 256 + threadIdx.x;
    if (i < E) atomicAdd(&deg[ei[E + i]], 1);
}

__global__ __launch_bounds__(256) void scan1_k(const int* __restrict__ deg, int* __restrict__ tmp,
                                               int* __restrict__ bsum, int n) {
    __shared__ int s[256];
    int tid = threadIdx.x;
    int i = blockIdx.x * 256 + tid;
    int v = (i < n) ? deg[i] : 0;
    s[tid] = v; __syncthreads();
    for (int o = 1; o < 256; o <<= 1) {
        int t = (tid >= o) ? s[tid - o] : 0;
        __syncthreads();
        s[tid] += t;
        __syncthreads();
    }
    if (i < n) tmp[i] = s[tid] - v;            // exclusive within block
    if (tid == 255) bsum[blockIdx.x] = s[255]; // block total
}

__global__ __launch_bounds__(512) void scan2_k(int* __restrict__ bsum, int nb) {
    __shared__ int s[512];
    int tid = threadIdx.x;
    int v = (tid < nb) ? bsum[tid] : 0;
    s[tid] = v; __syncthreads();
    for (int o = 1; o < 512; o <<= 1) {
        int t = (tid >= o) ? s[tid - o] : 0;
        __syncthreads();
        s[tid] += t;
        __syncthreads();
    }
    if (tid < nb) bsum[tid] = s[tid] - v;      // exclusive block offsets
}

__global__ __launch_bounds__(256) void scan3_k(const int* __restrict__ tmp, const int* __restrict__ bsum,
                                               int* __restrict__ off, int* __restrict__ cursor,
                                               int n, int Etot) {
    int i = blockIdx.x * 256 + threadIdx.x;
    if (i < n) {
        int v = tmp[i] + bsum[blockIdx.x];
        off[i] = v;
        cursor[i] = v;
    }
    if (i == 0) off[n] = Etot;
}

__global__ __launch_bounds__(256) void scatter_k(const int* __restrict__ ei, int* __restrict__ cursor,
                                                 int* __restrict__ csr, int E) {
    int i = blockIdx.x * 256 + threadIdx.x;
    if (i < E) {
        int d = ei[E + i];
        int p = atomicAdd(&cursor[d], 1);
        csr[p] = ei[i];
    }
}

// ---------------------------------------------------------------------------
// GEMM  H[n,64] = X[n,K] @ W[K,64]  + fused attention-logit epilogue.
// LANE = ROW: each lane owns a full 64-wide output row in registers.
//  - 64-way independent FMA ILP (no serial dot-product chain)
//  - W indexed wave-uniformly -> scalar loads via constant cache
//  - attention logits = per-lane register reduction (no shuffles)
// ---------------------------------------------------------------------------
template<int K, int HEADS>
__global__ __launch_bounds__(256) void gemm_al_k(const float* __restrict__ X, const float* __restrict__ W,
                                                 const float* __restrict__ a_s, const float* __restrict__ a_d,
                                                 float* __restrict__ H, float* __restrict__ ALS,
                                                 float* __restrict__ ALD, int n) {
    int row = blockIdx.x * 256 + threadIdx.x;
    if (row >= n) return;

    float acc[64];
#pragma unroll
    for (int c = 0; c < 64; c++) acc[c] = 0.f;

    const float4* xv = (const float4*)(X + (size_t)row * K);
#pragma unroll 1
    for (int k4 = 0; k4 < K / 4; k4++) {
        float4 xx = xv[k4];
#pragma unroll
        for (int j = 0; j < 4; j++) {
            float xs = (j == 0) ? xx.x : (j == 1) ? xx.y : (j == 2) ? xx.z : xx.w;
            const float* wr = W + (size_t)(k4 * 4 + j) * 64;   // wave-uniform -> s_load
#pragma unroll
            for (int c = 0; c < 64; c++) acc[c] += xs * wr[c];
        }
    }

    // attention logits: a layout is [head*32 + c] (flat), matches acc index
    if (HEADS == 2) {
        float s0 = 0.f, d0 = 0.f, s1 = 0.f, d1 = 0.f;
#pragma unroll
        for (int c = 0; c < 32; c++) {
            s0 += acc[c] * a_s[c];
            d0 += acc[c] * a_d[c];
            s1 += acc[32 + c] * a_s[32 + c];
            d1 += acc[32 + c] * a_d[32 + c];
        }
        ALS[(size_t)row * 2]     = s0;
        ALS[(size_t)row * 2 + 1] = s1;
        ALD[(size_t)row * 2]     = d0;
        ALD[(size_t)row * 2 + 1] = d1;
    } else {
        float s0 = 0.f, d0 = 0.f;
#pragma unroll
        for (int c = 0; c < 64; c++) {
            s0 += acc[c] * a_s[c];
            d0 += acc[c] * a_d[c];
        }
        ALS[row] = s0;
        ALD[row] = d0;
    }

    // store H row (contiguous 256B per lane, float4)
    float4* hv = (float4*)(H + (size_t)row * 64);
#pragma unroll
    for (int c4 = 0; c4 < 16; c4++) {
        hv[c4] = make_float4(acc[4 * c4], acc[4 * c4 + 1], acc[4 * c4 + 2], acc[4 * c4 + 3]);
    }
}

// ---------------------------------------------------------------------------
// Aggregation: one wave per dst node, lane = channel. Atomic-free.
// Softmax done without max-shift (scores are O(1), fp32-safe); self-loop inline.
// ---------------------------------------------------------------------------
template<int HEADS, int RELU>
__global__ __launch_bounds__(256) void aggregate_k(const float* __restrict__ H, const float* __restrict__ ALS,
                                                   const float* __restrict__ ALD, const int* __restrict__ off,
                                                   const int* __restrict__ csr, const float* __restrict__ bias,
                                                   float* __restrict__ OUT, int n) {
    int lane = threadIdx.x & 63;
    int dst = (blockIdx.x << 2) + (threadIdx.x >> 6);
    if (dst >= n) return;
    int head = (HEADS == 2) ? (lane >> 5) : 0;
    float ald = ALD[(size_t)dst * HEADS + head];

    // self-loop contribution
    float e = ALS[(size_t)dst * HEADS + head] + ald;
    e = (e >= 0.f) ? e : NEG_SLOPE * e;
    float ee = __expf(e);
    float den = ee;
    float acc = ee * H[(size_t)dst * 64 + lane];

    int b0 = off[dst], b1 = off[dst + 1];
    int i = b0;
    for (; i + 1 < b1; i += 2) {
        int s0 = csr[i], s1 = csr[i + 1];
        float e0 = ALS[(size_t)s0 * HEADS + head] + ald;
        float e1 = ALS[(size_t)s1 * HEADS + head] + ald;
        e0 = (e0 >= 0.f) ? e0 : NEG_SLOPE * e0;
        e1 = (e1 >= 0.f) ? e1 : NEG_SLOPE * e1;
        float w0 = __expf(e0);
        float w1 = __expf(e1);
        float h0 = H[(size_t)s0 * 64 + lane];
        float h1 = H[(size_t)s1 * 64 + lane];
        den += w0 + w1;
        acc += w0 * h0 + w1 * h1;
    }
    if (i < b1) {
        int s0 = csr[i];
        float e0 = ALS[(size_t)s0 * HEADS + head] + ald;
        e0 = (e0 >= 0.f) ? e0 : NEG_SLOPE * e0;
        float w0 = __expf(e0);
        den += w0;
        acc += w0 * H[(size_t)s0 * 64 + lane];
    }

    float o = acc / den + bias[lane];
    if (RELU) o = (o > 0.f) ? o : 0.f;
    OUT[(size_t)dst * 64 + lane] = o;
}

// ---------------------------------------------------------------------------
extern "C" void kernel_launch(void* const* d_in, const int* in_sizes, int n_in,
                              void* d_out, int out_size, void* d_ws, size_t ws_size,
                              hipStream_t stream) {
    const float* x   = (const float*)d_in[0];
    const int*   ei  = (const int*)  d_in[1];
    const float* W1  = (const float*)d_in[2];
    const float* as1 = (const float*)d_in[3];
    const float* ad1 = (const float*)d_in[4];
    const float* b1  = (const float*)d_in[5];
    const float* W2  = (const float*)d_in[6];
    const float* as2 = (const float*)d_in[7];
    const float* ad2 = (const float*)d_in[8];
    const float* b2  = (const float*)d_in[9];
    const float* W3  = (const float*)d_in[10];
    const float* as3 = (const float*)d_in[11];
    const float* ad3 = (const float*)d_in[12];
    const float* b3  = (const float*)d_in[13];

    const int N = in_sizes[0] / IN_CH;
    const int E = in_sizes[1] / 2;

    // workspace carve (256B aligned)
    char* p = (char*)d_ws;
    auto carve = [&](size_t bytes) {
        char* r = p;
        p += (bytes + 255) & ~(size_t)255;
        return r;
    };
    float* hbuf   = (float*)carve((size_t)N * HC * 4);
    float* obuf   = (float*)carve((size_t)N * HC * 4);
    float* als    = (float*)carve((size_t)N * 2 * 4);
    float* ald    = (float*)carve((size_t)N * 2 * 4);
    int*   deg    = (int*)  carve((size_t)N * 4);
    int*   cursor = (int*)  carve((size_t)N * 4);
    int*   off    = (int*)  carve((size_t)(N + 1) * 4);
    int*   tmp    = (int*)  carve((size_t)N * 4);
    int*   bsum   = (int*)  carve((size_t)((N + 255) / 256 + 1) * 4);
    int*   csr    = (int*)  carve((size_t)E * 4);

    const int NB = (N + 255) / 256;       // scan blocks (391 <= 512)
    const int EB = (E + 255) / 256;
    const int NW = (N + 3) / 4;           // aggregate: one wave per node, 4 waves/block

    // ---- CSR build (shared by all 3 layers) ----
    hipMemsetAsync(deg, 0, (size_t)N * 4, stream);
    hist_k   <<<EB, 256, 0, stream>>>(ei, deg, E);
    scan1_k  <<<NB, 256, 0, stream>>>(deg, tmp, bsum, N);
    scan2_k  <<<1, 512, 0, stream>>>(bsum, NB);
    scan3_k  <<<NB, 256, 0, stream>>>(tmp, bsum, off, cursor, N, E);
    scatter_k<<<EB, 256, 0, stream>>>(ei, cursor, csr, E);

    // ---- Layer 1: IN=128 -> 2x32 concat, relu ----
    gemm_al_k<128, 2><<<NB, 256, 0, stream>>>(x, W1, as1, ad1, hbuf, als, ald, N);
    aggregate_k<2, 1><<<NW, 256, 0, stream>>>(hbuf, als, ald, off, csr, b1, obuf, N);

    // ---- Layer 2: 64 -> 2x32 concat, relu ----
    gemm_al_k<64, 2><<<NB, 256, 0, stream>>>(obuf, W2, as2, ad2, hbuf, als, ald, N);
    aggregate_k<2, 1><<<NW, 256, 0, stream>>>(hbuf, als, ald, off, csr, b2, obuf, N);

    // ---- Layer 3: 64 -> 64, 1 head, mean(=identity), no relu ----
    gemm_al_k<64, 1><<<NB, 256, 0, stream>>>(obuf, W3, as3, ad3, hbuf, als, ald, N);
    aggregate_k<1, 0><<<NW, 256, 0, stream>>>(hbuf, als, ald, off, csr, b3, (float*)d_out, N);
}